// Round 11
// baseline (16365.010 us; speedup 1.0000x reference)
//
#include <hip/hip_runtime.h>
#include <hip/hip_bf16.h>

// NeuralODE Bosh3 fixed-step integrator, persistent-block formulation.
// Round 11: register-resident weights. 128 blocks x 256 threads (4 waves,
// launch_bounds(256,1) -> 512-VGPR budget). Per wave: 96 weight fragments
// pinned in VGPRs (W2 fully + W1 kt0..7 = 384 KB/CU resident); only
// W0 + W1 kt8..15 (416 KB/eval) stream via a continuous global_load_lds
// ring (3 x 8KB slots/wave), consume -> lgkmcnt(0) -> reissue into the
// just-consumed slot (fixes r9/r10 overwrite race), vmcnt(16) waits.
// Rationale: per-CU global streaming is walled at ~25-35 GB/s (measured
// across r2-r10 + m97/m13); residency is the only way below ~10 ms.

#define B_ 2048
#define L_ 128
#define P_ 8
#define T_ 128
#define BT_ 16
#define NBLK (B_/BT_)          // 128 blocks

typedef __attribute__((ext_vector_type(8))) short short8;
typedef __attribute__((ext_vector_type(4))) float f32x4;

// fragment = 512 ushorts (64 lanes x 16B). Region layout in wp (frag units):
// R0 [0,160):   W0 streamed,  f = (wv*5 + kt)*8 + ntl,  nt = wv*8+ntl, kt 0..4
// R1 [160,416): W1hi streamed,f-160 = (wv*8 + kk)*8+ntl, kt = 8+kk
// R2 [416,672): W1lo resident,f-416 = (wv*8 + kt)*8+ntl, kt 0..7
// R3 [672,800): W2 resident,  f-672 = (wv*2 + ntl)*16+kt, nt = 2wv+ntl
#define R1F 160
#define R2F 416
#define R3F 672
#define NFRAG 800
#define WTOT (NFRAG*512)       // 409600 ushorts = 800 KiB

#define VMW16 asm volatile("s_waitcnt vmcnt(16)" ::: "memory")
#define VMW0  asm volatile("s_waitcnt vmcnt(0)"  ::: "memory")
#define LKW0  asm volatile("s_waitcnt lgkmcnt(0)" ::: "memory")

__device__ __forceinline__ unsigned short f2bf(float f){
  unsigned u = __builtin_bit_cast(unsigned, f);
  u += 0x7fffu + ((u >> 16) & 1u);          // round-to-nearest-even
  return (unsigned short)(u >> 16);
}

__device__ __forceinline__ float tanh_fast(float x){
  float e = __expf(2.0f * x);
  return 1.0f - __fdividef(2.0f, e + 1.0f); // exact at saturation (+-1)
}

// async 16B/lane global->LDS: LDS dest = uniform base + lane*16
__device__ __forceinline__ void gld16(const unsigned short* g, unsigned short* l){
  __builtin_amdgcn_global_load_lds(
      (const __attribute__((address_space(1))) unsigned int*)(const void*)g,
      (__attribute__((address_space(3))) unsigned int*)(void*)l,
      16, 0, 0);
}

// Pack weights into the fragment regions above. Fragment element layout:
// elem = frag*512 + lane*8 + j  <-  bf16(W[nt*16+(lane&15)][kt*32+(lane>>4)*8+j])
// idx in [WTOT, WTOT+T_-1): dts[idx-WTOT] = ts[i+1]-ts[i] (fp32) at wp+WTOT.
__global__ void prep_weights(const float* __restrict__ W0,
                             const float* __restrict__ W1,
                             const float* __restrict__ W2,
                             const float* __restrict__ ts,
                             unsigned short* __restrict__ wp){
  int idx = blockIdx.x * blockDim.x + threadIdx.x;
  if (idx >= WTOT){
    int t = idx - WTOT;
    if (t < T_ - 1){
      float* dts = (float*)(wp + WTOT);
      dts[t] = ts[t+1] - ts[t];
    }
    return;
  }
  int e = idx & 511, frag = idx >> 9;
  int j = e & 7, lane = e >> 3;
  const float* src; int nt, kt, Korig;
  if (frag < R1F){                    // W0 streamed
    int f = frag; int ntl = f & 7; int r = f >> 3; kt = r % 5; int wv = r / 5;
    nt = wv*8 + ntl; src = W0; Korig = 136;
  } else if (frag < R2F){             // W1 kt8..15 streamed
    int f = frag - R1F; int ntl = f & 7; int r = f >> 3; int kk = r & 7; int wv = r >> 3;
    kt = 8 + kk; nt = wv*8 + ntl; src = W1; Korig = 512;
  } else if (frag < R3F){             // W1 kt0..7 resident
    int f = frag - R2F; int ntl = f & 7; int r = f >> 3; kt = r & 7; int wv = r >> 3;
    nt = wv*8 + ntl; src = W1; Korig = 512;
  } else {                            // W2 resident
    int f = frag - R3F; kt = f & 15; int r = f >> 4; int ntl = r & 1; int wv = r >> 1;
    nt = wv*2 + ntl; src = W2; Korig = 512;
  }
  int row = nt*16 + (lane & 15);
  int k   = kt*32 + ((lane >> 4) << 3) + j;
  float v = (k < Korig) ? src[row*Korig + k] : 0.0f;
  wp[idx] = f2bf(v);
}

// LDS act layouts (bf16, XOR-swizzled: byte ^= (row&7)<<4 within the row).
#define XROWB 384    // x: 192 ushorts/row (0..127 y, 128..135 args, rest 0)
#define HROWB 1024   // h: 512 ushorts/row

__global__ __launch_bounds__(256, 1)
void ode_main(const float* __restrict__ x0,
              const float* __restrict__ args,
              const float* __restrict__ b0, const float* __restrict__ b1,
              const float* __restrict__ b2,
              const unsigned short* __restrict__ wp,
              float* __restrict__ out){
  __shared__ __align__(16) unsigned short xb[BT_*(XROWB/2)];   // 6 KiB
  __shared__ __align__(16) unsigned short h1[BT_*(HROWB/2)];   // 16 KiB
  __shared__ __align__(16) unsigned short h2[BT_*(HROWB/2)];   // 16 KiB
  __shared__ __align__(16) float ybuf[BT_][L_];                // 8 KiB
  __shared__ __align__(16) unsigned short wsl[4*3*4096];       // 96 KiB ring slots
  __shared__ float dtl[T_];                                    // 512 B
  __shared__ float b0l[512], b1l[512], b2l[128];               // 4.5 KiB

  const int tid  = threadIdx.x;
  const int lane = tid & 63;
  const int wv   = tid >> 6;     // wave 0..3
  const int lo   = lane & 15;
  const int hi   = lane >> 4;    // 0..3
  const int r0   = blockIdx.x * BT_;
  const int aswz = (lo & 7) << 4;

  // ---- resident weights into registers (static indices throughout)
  short8 w1r[64];   // [kt0..7][ntl0..7] -> w1r[kt*8+ntl]
  short8 w2r[32];   // [ntl0..1][kt0..15] -> w2r[ntl*16+kt]
  {
    const unsigned short* p = wp + (size_t)(R2F + wv*64)*512 + lane*8;
    #pragma unroll
    for (int i = 0; i < 64; ++i) w1r[i] = *(const short8*)(p + (size_t)i*512);
  }
  {
    const unsigned short* p = wp + (size_t)(R3F + wv*32)*512 + lane*8;
    #pragma unroll
    for (int i = 0; i < 32; ++i) w2r[i] = *(const short8*)(p + (size_t)i*512);
  }

  // ---- biases + dts into LDS (keeps registers for weights)
  for (int i = tid; i < 512; i += 256){ b0l[i] = b0[i]; b1l[i] = b1[i]; }
  if (tid < 128) b2l[tid] = b2[tid];
  if (tid < T_-1) dtl[tid] = ((const float*)(wp + WTOT))[tid];

  // zero xb (zeroes are swizzle-invariant)
  for (int i = tid; i < BT_*(XROWB/2); i += 256) xb[i] = 0;
  __syncthreads();

  // args -> x cols 128..135 (constant across all steps)
  if (tid < BT_*P_){
    int r = tid >> 3, pp = tid & 7;
    unsigned short v = f2bf(args[(r0 + r)*P_ + pp]);
    *(unsigned short*)((char*)xb + r*XROWB + (((128 + pp)*2) ^ ((r & 7) << 4))) = v;
  }

  // ODE state: thread owns cols c=(2wv+ntl)*16+lo (ntl 0..1), rows 4hi+j
  float yr[2][4], yn[2][4];
  #pragma unroll
  for (int n = 0; n < 2; ++n)
    #pragma unroll
    for (int j = 0; j < 4; ++j){
      int row = 4*hi + j, c = (2*wv + n)*16 + lo;
      float v = x0[(r0 + row)*L_ + c];
      yr[n][j] = v;
      ybuf[row][c] = v;
      *(unsigned short*)((char*)xb + row*XROWB + ((c*2) ^ ((row & 7) << 4))) = f2bf(v);
    }
  __syncthreads();

  // store slice t=0 (full 512B rows, 2 x f32x4 per thread)
  {
    int row = tid >> 4, cb = (tid & 15) * 8;
    f32x4 v0 = *(const f32x4*)&ybuf[row][cb];
    f32x4 v1 = *(const f32x4*)&ybuf[row][cb + 4];
    __builtin_nontemporal_store(v0, (f32x4*)&out[((r0 + row)*T_ + 0)*L_ + cb]);
    __builtin_nontemporal_store(v1, (f32x4*)&out[((r0 + row)*T_ + 0)*L_ + cb + 4]);
  }
  VMW0;   // drain everything (resident loads + stores) before manual counting

  // ---- continuous stream ring: 13 groups/eval (W0 g0..4, W1hi g5..12)
  const unsigned short* w0s = wp + (size_t)(wv*40)*512 + lane*8;
  const unsigned short* w1s = wp + (size_t)(R1F + wv*64)*512 + lane*8;
  unsigned short* wslw = wsl + wv*3*4096;
  int ns = 0;    // next stream group index (0..12)
  int scs = 0;   // current ring slot (0..2); issue goes into just-consumed slot
  auto issue_next = [&]{
    const unsigned short* g = (ns < 5) ? (w0s + (size_t)ns*4096)
                                       : (w1s + (size_t)(ns - 5)*4096);
    unsigned short* d = wslw + scs*4096;
    #pragma unroll
    for (int q = 0; q < 8; ++q) gld16(g + (size_t)q*512, d + q*512);
    ns  = (ns == 12) ? 0 : ns + 1;
    scs = (scs == 2) ? 0 : scs + 1;
  };
  issue_next(); issue_next(); issue_next();   // prologue: G0,G1,G2 in flight

  // ---- one vector-field eval (consumes 13 groups, issues 13)
  auto evalf = [&](f32x4 (&dout)[2]){
    f32x4 acc[8];
    // layer 1: 5 streamed kts, 8 nt/wave
    #pragma unroll
    for (int n = 0; n < 8; ++n) acc[n] = f32x4{0,0,0,0};
    #pragma unroll
    for (int kt = 0; kt < 5; ++kt){
      VMW16;
      const unsigned short* csl = wslw + scs*4096;
      short8 a0 = *(const short8*)((const char*)xb + lo*XROWB + ((kt*64 + hi*16) ^ aswz));
      #pragma unroll
      for (int n = 0; n < 8; ++n){
        short8 wf = *(const short8*)(csl + n*512 + lane*8);
        acc[n] = __builtin_amdgcn_mfma_f32_16x16x32_bf16(a0, wf, acc[n], 0, 0, 0);
      }
      LKW0;             // all slot reads hardware-complete before overwrite
      issue_next();
    }
    #pragma unroll
    for (int n = 0; n < 8; ++n)
      #pragma unroll
      for (int j = 0; j < 4; ++j){
        int col = (wv*8 + n)*16 + lo;
        float v = tanh_fast(acc[n][j] + b0l[col]);
        int row = 4*hi + j;
        *(unsigned short*)((char*)h1 + row*HROWB + ((col*2) ^ ((row & 7) << 4))) = f2bf(v);
      }
    __syncthreads();
    // layer 2: 8 resident kts (VGPR weights) then 8 streamed kts
    #pragma unroll
    for (int n = 0; n < 8; ++n) acc[n] = f32x4{0,0,0,0};
    #pragma unroll
    for (int kt = 0; kt < 8; ++kt){
      short8 a0 = *(const short8*)((const char*)h1 + lo*HROWB + ((kt*64 + hi*16) ^ aswz));
      #pragma unroll
      for (int n = 0; n < 8; ++n)
        acc[n] = __builtin_amdgcn_mfma_f32_16x16x32_bf16(a0, w1r[kt*8 + n], acc[n], 0, 0, 0);
    }
    #pragma unroll
    for (int kk = 0; kk < 8; ++kk){
      VMW16;
      const unsigned short* csl = wslw + scs*4096;
      short8 a0 = *(const short8*)((const char*)h1 + lo*HROWB + (((8 + kk)*64 + hi*16) ^ aswz));
      #pragma unroll
      for (int n = 0; n < 8; ++n){
        short8 wf = *(const short8*)(csl + n*512 + lane*8);
        acc[n] = __builtin_amdgcn_mfma_f32_16x16x32_bf16(a0, wf, acc[n], 0, 0, 0);
      }
      LKW0;
      issue_next();
    }
    #pragma unroll
    for (int n = 0; n < 8; ++n)
      #pragma unroll
      for (int j = 0; j < 4; ++j){
        int col = (wv*8 + n)*16 + lo;
        float v = tanh_fast(acc[n][j] + b1l[col]);
        int row = 4*hi + j;
        *(unsigned short*)((char*)h2 + row*HROWB + ((col*2) ^ ((row & 7) << 4))) = f2bf(v);
      }
    __syncthreads();
    // layer 3: fully resident; wave owns nt = 2wv, 2wv+1
    f32x4 a3[2];
    a3[0] = f32x4{0,0,0,0};
    a3[1] = f32x4{0,0,0,0};
    #pragma unroll
    for (int kt = 0; kt < 16; ++kt){
      short8 a0 = *(const short8*)((const char*)h2 + lo*HROWB + ((kt*64 + hi*16) ^ aswz));
      a3[0] = __builtin_amdgcn_mfma_f32_16x16x32_bf16(a0, w2r[kt],      a3[0], 0, 0, 0);
      a3[1] = __builtin_amdgcn_mfma_f32_16x16x32_bf16(a0, w2r[16 + kt], a3[1], 0, 0, 0);
    }
    dout[0] = a3[0];
    dout[1] = a3[1];
  };

  // Bosh3: k1=f(y); k2=f(y+dt/2 k1); k3=f(y+3dt/4 k2); y+=dt(2/9 k1+1/3 k2+4/9 k3)
  for (int t = 1; t < T_; ++t){
    float dt = dtl[t-1];
    f32x4 d[2];

    evalf(d);                              // k1
    #pragma unroll
    for (int n = 0; n < 2; ++n)
      #pragma unroll
      for (int j = 0; j < 4; ++j){
        int c = (2*wv + n)*16 + lo;
        float k = d[n][j] + b2l[c];
        yn[n][j] = yr[n][j] + dt*(2.0f/9.0f)*k;
        float xs = yr[n][j] + 0.5f*dt*k;
        int row = 4*hi + j;
        *(unsigned short*)((char*)xb + row*XROWB + ((c*2) ^ ((row & 7) << 4))) = f2bf(xs);
      }
    __syncthreads();

    evalf(d);                              // k2
    #pragma unroll
    for (int n = 0; n < 2; ++n)
      #pragma unroll
      for (int j = 0; j < 4; ++j){
        int c = (2*wv + n)*16 + lo;
        float k = d[n][j] + b2l[c];
        yn[n][j] += dt*(1.0f/3.0f)*k;
        float xs = yr[n][j] + 0.75f*dt*k;
        int row = 4*hi + j;
        *(unsigned short*)((char*)xb + row*XROWB + ((c*2) ^ ((row & 7) << 4))) = f2bf(xs);
      }
    __syncthreads();

    evalf(d);                              // k3
    #pragma unroll
    for (int n = 0; n < 2; ++n)
      #pragma unroll
      for (int j = 0; j < 4; ++j){
        int c = (2*wv + n)*16 + lo;
        float k = d[n][j] + b2l[c];
        yn[n][j] += dt*(4.0f/9.0f)*k;
        yr[n][j] = yn[n][j];
        int row = 4*hi + j;
        ybuf[row][c] = yr[n][j];
        *(unsigned short*)((char*)xb + row*XROWB + ((c*2) ^ ((row & 7) << 4))) = f2bf(yr[n][j]);
      }
    __syncthreads();

    // store slice t (full 512B rows from ybuf)
    {
      int row = tid >> 4, cb = (tid & 15) * 8;
      f32x4 v0 = *(const f32x4*)&ybuf[row][cb];
      f32x4 v1 = *(const f32x4*)&ybuf[row][cb + 4];
      __builtin_nontemporal_store(v0, (f32x4*)&out[((r0 + row)*T_ + t)*L_ + cb]);
      __builtin_nontemporal_store(v1, (f32x4*)&out[((r0 + row)*T_ + t)*L_ + cb + 4]);
    }
    VMW0;   // drain store-acks; in-flight ring groups have long landed
  }
}

extern "C" void kernel_launch(void* const* d_in, const int* in_sizes, int n_in,
                              void* d_out, int out_size, void* d_ws, size_t ws_size,
                              hipStream_t stream) {
  const float* x0   = (const float*)d_in[0];
  const float* ts   = (const float*)d_in[1];
  const float* args = (const float*)d_in[2];
  const float* W0   = (const float*)d_in[3];
  const float* b0   = (const float*)d_in[4];
  const float* W1   = (const float*)d_in[5];
  const float* b1   = (const float*)d_in[6];
  const float* W2   = (const float*)d_in[7];
  const float* b2   = (const float*)d_in[8];
  unsigned short* wp = (unsigned short*)d_ws;   // 819,200 B weights + 512 B dts
  float* out = (float*)d_out;

  prep_weights<<<(WTOT + T_ + 255)/256, 256, 0, stream>>>(W0, W1, W2, ts, wp);
  ode_main<<<NBLK, 256, 0, stream>>>(x0, args, b0, b1, b2, wp, out);
}

// Round 12
// 9548.099 us; speedup vs baseline: 1.7140x; 1.7140x over previous
//
#include <hip/hip_runtime.h>
#include <hip/hip_bf16.h>

// NeuralODE Bosh3 fixed-step integrator, persistent-block formulation.
// Round 12: clean deep-pipelined weight streaming. 128 blocks x 512 thr
// (8 waves, BT=16). No resident weights (r11: 256-VGPR ceiling makes them
// spill). Weights packed as 25 contiguous 4KB groups per wave (100 KB
// wave-private stream/eval); per-wave 3x4KB LDS ring; audited counts:
// ISSUE(g+2) -> vmcnt(8) -> consume -> lgkmcnt(0) -> overwrite-next-iter.
// Slot of G(k) = k%3 so the overwrite of slot g%3 is G(g+3), issued only
// after g's reads retired (fixes r10 race; fixes r9 overwait).

#define B_ 2048
#define L_ 128
#define P_ 8
#define T_ 128
#define BT_ 16
#define NBLK (B_/BT_)          // 128 blocks

typedef __attribute__((ext_vector_type(8))) short short8;
typedef __attribute__((ext_vector_type(4))) float f32x4;

// 800 fragments x 512 ushorts = 800 KB. Per wave: 25 groups x 4 frags.
// group g of wave wv at wp + (wv*100 + g*4)*512:
//   g in [0,5):  W0, kt=g,        nt=wv*4+q   (Kpad 160, K=136)
//   g in [5,21): W1, kt=g-5,      nt=wv*4+q
//   g in [21,25):W2, kt=4(g-21)+q, nt=wv
#define WTOT (800*512)         // 409600 ushorts = 819200 B

#define VMW8 asm volatile("s_waitcnt vmcnt(8)" ::: "memory")
#define VMW4 asm volatile("s_waitcnt vmcnt(4)" ::: "memory")
#define VMW0 asm volatile("s_waitcnt vmcnt(0)" ::: "memory")
#define LKW0 asm volatile("s_waitcnt lgkmcnt(0)" ::: "memory")
#define SCHB __builtin_amdgcn_sched_barrier(0)

__device__ __forceinline__ unsigned short f2bf(float f){
  unsigned u = __builtin_bit_cast(unsigned, f);
  u += 0x7fffu + ((u >> 16) & 1u);          // round-to-nearest-even
  return (unsigned short)(u >> 16);
}

__device__ __forceinline__ float tanh_fast(float x){
  float e = __expf(2.0f * x);
  return 1.0f - __fdividef(2.0f, e + 1.0f); // exact at saturation (+-1)
}

// async 16B/lane global->LDS: LDS dest = uniform base + lane*16
__device__ __forceinline__ void gld16(const unsigned short* g, unsigned short* l){
  __builtin_amdgcn_global_load_lds(
      (const __attribute__((address_space(1))) unsigned int*)(const void*)g,
      (__attribute__((address_space(3))) unsigned int*)(void*)l,
      16, 0, 0);
}

// Fragment element: frag f, lane, j -> bf16(W[nt*16+(lane&15)][kt*32+(lane>>4)*8+j])
// idx in [WTOT, WTOT+T_-1): dts[idx-WTOT] = ts[i+1]-ts[i] (fp32) at wp+WTOT.
__global__ void prep_weights(const float* __restrict__ W0,
                             const float* __restrict__ W1,
                             const float* __restrict__ W2,
                             const float* __restrict__ ts,
                             unsigned short* __restrict__ wp){
  int idx = blockIdx.x * blockDim.x + threadIdx.x;
  if (idx >= WTOT){
    int t = idx - WTOT;
    if (t < T_ - 1){
      float* dts = (float*)(wp + WTOT);
      dts[t] = ts[t+1] - ts[t];
    }
    return;
  }
  int e = idx & 511, f = idx >> 9;
  int j = e & 7, lane = e >> 3;
  int wv = f / 100, r = f % 100;
  int g = r >> 2, q = r & 3;
  const float* src; int nt, kt, Korig;
  if (g < 5)      { src = W0; Korig = 136; kt = g;           nt = wv*4 + q; }
  else if (g < 21){ src = W1; Korig = 512; kt = g - 5;       nt = wv*4 + q; }
  else            { src = W2; Korig = 512; kt = 4*(g-21) + q; nt = wv; }
  int row = nt*16 + (lane & 15);
  int k   = kt*32 + ((lane >> 4) << 3) + j;
  float v = (k < Korig) ? src[row*Korig + k] : 0.0f;
  wp[idx] = f2bf(v);
}

// LDS act layouts (bf16, XOR-swizzled: byte ^= (row&7)<<4 within the row).
#define XROWB 384    // x: 192 ushorts/row (0..127 y, 128..135 args, rest 0)
#define HROWB 1024   // h: 512 ushorts/row

__global__ __launch_bounds__(512, 2)
void ode_main(const float* __restrict__ x0,
              const float* __restrict__ args,
              const float* __restrict__ b0, const float* __restrict__ b1,
              const float* __restrict__ b2,
              const unsigned short* __restrict__ wp,
              float* __restrict__ out){
  __shared__ __align__(16) unsigned short xb[BT_*(XROWB/2)];   // 6 KiB
  __shared__ __align__(16) unsigned short h1[BT_*(HROWB/2)];   // 16 KiB
  __shared__ __align__(16) unsigned short h2[BT_*(HROWB/2)];   // 16 KiB
  __shared__ __align__(16) float ybuf[BT_][L_];                // 8 KiB
  __shared__ __align__(16) unsigned short wsl[8*3*2048];       // 96 KiB rings
  __shared__ float b0l[512], b1l[512], b2l[128], dtl[T_];      // 4.9 KiB

  const int tid  = threadIdx.x;
  const int lane = tid & 63;
  const int wv   = tid >> 6;     // wave 0..7
  const int lo   = lane & 15;
  const int hi   = lane >> 4;    // 0..3
  const int r0   = blockIdx.x * BT_;
  const int aswz = (lo & 7) << 4;

  // per-lane stream base (25 groups x 2048 ushorts, wave-private)
  const unsigned short* wsrc = wp + (size_t)wv*51200 + lane*8;
  unsigned short* wslw = wsl + wv*6144;   // 3 slots x 2048 ushorts

  // biases + dts into LDS
  for (int i = tid; i < 512; i += 512){ b0l[i] = b0[i]; b1l[i] = b1[i]; }
  if (tid < 128) b2l[tid] = b2[tid];
  if (tid < T_-1) dtl[tid] = ((const float*)(wp + WTOT))[tid];

  // zero xb (zeroes are swizzle-invariant)
  for (int i = tid; i < BT_*(XROWB/2); i += 512) xb[i] = 0;
  __syncthreads();

  // args -> x cols 128..135
  if (tid < BT_*P_){
    int r = tid >> 3, pp = tid & 7;
    unsigned short v = f2bf(args[(r0 + r)*P_ + pp]);
    *(unsigned short*)((char*)xb + r*XROWB + (((128 + pp)*2) ^ ((r & 7) << 4))) = v;
  }

  // ODE state: rows 4hi+j, col c3 = wv*16+lo
  const int c3 = wv*16 + lo;
  float yr[4], yn[4];
  #pragma unroll
  for (int j = 0; j < 4; ++j){
    int row = 4*hi + j;
    float v = x0[(r0 + row)*L_ + c3];
    yr[j] = v;
    ybuf[row][c3] = v;
    *(unsigned short*)((char*)xb + row*XROWB + ((c3*2) ^ ((row & 7) << 4))) = f2bf(v);
  }
  __syncthreads();

  // store slice t=0 (full 512B rows: 512 threads x 1 f32x4)
  {
    int row = tid >> 5, c4 = (tid & 31) << 2;
    f32x4 v = *(const f32x4*)&ybuf[row][c4];
    __builtin_nontemporal_store(v, (f32x4*)&out[((r0 + row)*T_ + 0)*L_ + c4]);
  }

  // issue group g into slot g%3 (static under unroll)
  auto ISSUE = [&](int g){
    if (g < 25){
      const unsigned short* src = wsrc + (size_t)g*2048;
      unsigned short* dst = wslw + (g % 3)*2048;
      #pragma unroll
      for (int q = 0; q < 4; ++q) gld16(src + (size_t)q*512, dst + q*512);
    }
  };

  // one vector-field eval; precondition: G0,G1 issued (or landed) in slots 0,1
  auto evalf = [&](f32x4& dout){
    f32x4 acc[4];
    // ---- layer 1: groups 0..4 (kt = g)
    #pragma unroll
    for (int n = 0; n < 4; ++n) acc[n] = f32x4{0,0,0,0};
    #pragma unroll
    for (int g = 0; g < 5; ++g){
      ISSUE(g+2);
      VMW8; SCHB;
      const unsigned short* sl = wslw + (g % 3)*2048;
      short8 a0 = *(const short8*)((const char*)xb + lo*XROWB + ((g*64 + hi*16) ^ aswz));
      #pragma unroll
      for (int n = 0; n < 4; ++n){
        short8 wf = *(const short8*)(sl + n*512 + lane*8);
        acc[n] = __builtin_amdgcn_mfma_f32_16x16x32_bf16(a0, wf, acc[n], 0, 0, 0);
      }
      LKW0;
    }
    #pragma unroll
    for (int n = 0; n < 4; ++n)
      #pragma unroll
      for (int j = 0; j < 4; ++j){
        int col = (wv*4 + n)*16 + lo;
        float v = tanh_fast(acc[n][j] + b0l[col]);
        int row = 4*hi + j;
        *(unsigned short*)((char*)h1 + row*HROWB + ((col*2) ^ ((row & 7) << 4))) = f2bf(v);
      }
    __syncthreads();
    // ---- layer 2: groups 5..20 (kt = g-5)
    #pragma unroll
    for (int n = 0; n < 4; ++n) acc[n] = f32x4{0,0,0,0};
    #pragma unroll
    for (int g = 5; g < 21; ++g){
      ISSUE(g+2);
      VMW8; SCHB;
      const unsigned short* sl = wslw + (g % 3)*2048;
      short8 a0 = *(const short8*)((const char*)h1 + lo*HROWB + (((g-5)*64 + hi*16) ^ aswz));
      #pragma unroll
      for (int n = 0; n < 4; ++n){
        short8 wf = *(const short8*)(sl + n*512 + lane*8);
        acc[n] = __builtin_amdgcn_mfma_f32_16x16x32_bf16(a0, wf, acc[n], 0, 0, 0);
      }
      LKW0;
    }
    #pragma unroll
    for (int n = 0; n < 4; ++n)
      #pragma unroll
      for (int j = 0; j < 4; ++j){
        int col = (wv*4 + n)*16 + lo;
        float v = tanh_fast(acc[n][j] + b1l[col]);
        int row = 4*hi + j;
        *(unsigned short*)((char*)h2 + row*HROWB + ((col*2) ^ ((row & 7) << 4))) = f2bf(v);
      }
    __syncthreads();
    // ---- layer 3: groups 21..24, 4 kts each (kt = 4(g-21)+q), nt = wv
    f32x4 a3 = f32x4{0,0,0,0};
    #pragma unroll
    for (int g = 21; g < 25; ++g){
      ISSUE(g+2);                           // nop for g >= 23
      if (g <= 22){ VMW8; } else if (g == 23){ VMW4; } else { VMW0; }
      SCHB;
      const unsigned short* sl = wslw + (g % 3)*2048;
      #pragma unroll
      for (int q = 0; q < 4; ++q){
        int kt = 4*(g-21) + q;
        short8 a0 = *(const short8*)((const char*)h2 + lo*HROWB + ((kt*64 + hi*16) ^ aswz));
        short8 wf = *(const short8*)(sl + q*512 + lane*8);
        a3 = __builtin_amdgcn_mfma_f32_16x16x32_bf16(a0, wf, a3, 0, 0, 0);
      }
      LKW0;
    }
    // prime next eval (slot0 = just-consumed G24's slot, slot1 = G22's)
    ISSUE(0);
    ISSUE(1);
    dout = a3;
  };

  VMW0;              // drain init loads/stores before counted ring
  ISSUE(0); ISSUE(1);
  __syncthreads();   // drains vmcnt -> slots 0,1 valid; xb ready

  // Bosh3: k1=f(y); k2=f(y+dt/2 k1); k3=f(y+3dt/4 k2); y+=dt(2/9k1+1/3k2+4/9k3)
  for (int t = 1; t < T_; ++t){
    float dt = dtl[t-1];
    f32x4 d;

    evalf(d);                              // k1
    #pragma unroll
    for (int j = 0; j < 4; ++j){
      float k = d[j] + b2l[c3];
      yn[j] = yr[j] + dt*(2.0f/9.0f)*k;
      float xs = yr[j] + 0.5f*dt*k;
      int row = 4*hi + j;
      *(unsigned short*)((char*)xb + row*XROWB + ((c3*2) ^ ((row & 7) << 4))) = f2bf(xs);
    }
    __syncthreads();

    evalf(d);                              // k2
    #pragma unroll
    for (int j = 0; j < 4; ++j){
      float k = d[j] + b2l[c3];
      yn[j] += dt*(1.0f/3.0f)*k;
      float xs = yr[j] + 0.75f*dt*k;
      int row = 4*hi + j;
      *(unsigned short*)((char*)xb + row*XROWB + ((c3*2) ^ ((row & 7) << 4))) = f2bf(xs);
    }
    __syncthreads();

    evalf(d);                              // k3
    #pragma unroll
    for (int j = 0; j < 4; ++j){
      float k = d[j] + b2l[c3];
      yn[j] += dt*(4.0f/9.0f)*k;
      yr[j] = yn[j];
      int row = 4*hi + j;
      ybuf[row][c3] = yr[j];
      *(unsigned short*)((char*)xb + row*XROWB + ((c3*2) ^ ((row & 7) << 4))) = f2bf(yr[j]);
    }
    __syncthreads();                       // xb + ybuf ready; drains primes

    {                                      // store y_t (1 f32x4/thread; the
      int row = tid >> 5, c4 = (tid & 31) << 2;   // 1 outstanding store is
      f32x4 v = *(const f32x4*)&ybuf[row][c4];    // covered by next VMW8)
      __builtin_nontemporal_store(v, (f32x4*)&out[((r0 + row)*T_ + t)*L_ + c4]);
    }
  }
}

extern "C" void kernel_launch(void* const* d_in, const int* in_sizes, int n_in,
                              void* d_out, int out_size, void* d_ws, size_t ws_size,
                              hipStream_t stream) {
  const float* x0   = (const float*)d_in[0];
  const float* ts   = (const float*)d_in[1];
  const float* args = (const float*)d_in[2];
  const float* W0   = (const float*)d_in[3];
  const float* b0   = (const float*)d_in[4];
  const float* W1   = (const float*)d_in[5];
  const float* b1   = (const float*)d_in[6];
  const float* W2   = (const float*)d_in[7];
  const float* b2   = (const float*)d_in[8];
  unsigned short* wp = (unsigned short*)d_ws;   // 819,200 B weights + 512 B dts
  float* out = (float*)d_out;

  prep_weights<<<(WTOT + T_ + 255)/256, 256, 0, stream>>>(W0, W1, W2, ts, wp);
  ode_main<<<NBLK, 512, 0, stream>>>(x0, args, b0, b1, b2, wp, out);
}